// Round 2
// baseline (284.593 us; speedup 1.0000x reference)
//
#include <hip/hip_runtime.h>
#include <stdint.h>

#define B_DIM 64
#define C_DIM 3
#define HM 512
#define WM_META 513
#define WM 512
#define OSIZE 224
#define N_TRIES 10

// ---------------- Threefry-2x32 (20 rounds), exactly JAX's ----------------
__device__ __forceinline__ uint32_t rotl32(uint32_t v, int d) {
    return (v << d) | (v >> (32 - d));
}

__device__ __forceinline__ void threefry2x32(uint32_t k0, uint32_t k1,
                                             uint32_t x0, uint32_t x1,
                                             uint32_t& o0, uint32_t& o1) {
    const uint32_t ks0 = k0, ks1 = k1, ks2 = k0 ^ k1 ^ 0x1BD11BDAu;
    x0 += ks0; x1 += ks1;
    // rounds 1-4: rot {13,15,26,6}, inject (ks1, ks2+1)
    x0 += x1; x1 = rotl32(x1, 13); x1 ^= x0;
    x0 += x1; x1 = rotl32(x1, 15); x1 ^= x0;
    x0 += x1; x1 = rotl32(x1, 26); x1 ^= x0;
    x0 += x1; x1 = rotl32(x1,  6); x1 ^= x0;
    x0 += ks1; x1 += ks2 + 1u;
    // rounds 5-8: rot {17,29,16,24}, inject (ks2, ks0+2)
    x0 += x1; x1 = rotl32(x1, 17); x1 ^= x0;
    x0 += x1; x1 = rotl32(x1, 29); x1 ^= x0;
    x0 += x1; x1 = rotl32(x1, 16); x1 ^= x0;
    x0 += x1; x1 = rotl32(x1, 24); x1 ^= x0;
    x0 += ks2; x1 += ks0 + 2u;
    // rounds 9-12
    x0 += x1; x1 = rotl32(x1, 13); x1 ^= x0;
    x0 += x1; x1 = rotl32(x1, 15); x1 ^= x0;
    x0 += x1; x1 = rotl32(x1, 26); x1 ^= x0;
    x0 += x1; x1 = rotl32(x1,  6); x1 ^= x0;
    x0 += ks0; x1 += ks1 + 3u;
    // rounds 13-16
    x0 += x1; x1 = rotl32(x1, 17); x1 ^= x0;
    x0 += x1; x1 = rotl32(x1, 29); x1 ^= x0;
    x0 += x1; x1 = rotl32(x1, 16); x1 ^= x0;
    x0 += x1; x1 = rotl32(x1, 24); x1 ^= x0;
    x0 += ks1; x1 += ks2 + 4u;
    // rounds 17-20
    x0 += x1; x1 = rotl32(x1, 13); x1 ^= x0;
    x0 += x1; x1 = rotl32(x1, 15); x1 ^= x0;
    x0 += x1; x1 = rotl32(x1, 26); x1 ^= x0;
    x0 += x1; x1 = rotl32(x1,  6); x1 ^= x0;
    x0 += ks2; x1 += ks0 + 5u;
    o0 = x0; o1 = x1;
}

// Partitionable-threefry uniform (JAX >= 0.4.30 default):
// element b of uniform(key,(64,)): counter = 64-bit iota -> (hi=0, lo=b);
// 32-bit bits = word0 ^ word1; float = bitcast((bits>>9)|0x3f800000)-1;
// val = u*(hi-lo)+lo (separate mul/add, XLA doesn't contract); max(lo, val).
__device__ __forceinline__ float jax_uniform_elem(uint32_t k0, uint32_t k1, int b,
                                                  float lo, float hi) {
#pragma clang fp contract(off)
    uint32_t w0, w1;
    threefry2x32(k0, k1, 0u, (uint32_t)b, w0, w1);
    uint32_t bits = w0 ^ w1;
    uint32_t fb = (bits >> 9) | 0x3f800000u;
    float u = __uint_as_float(fb) - 1.0f;   // [0,1)
    float d = hi - lo;
    float v = u * d + lo;
    return fmaxf(lo, v);
}

// ---------------- Kernel 1: per-batch params (flip, i, j, h, w) -----------
__global__ void __launch_bounds__(64)
params_kernel(const float* __restrict__ x, int* __restrict__ params) {
#pragma clang fp contract(off)
    int b = threadIdx.x;
    if (b >= B_DIM) return;

    // root key = jax.random.key(42) -> (0, 42)
    // partitionable split: child i = both words of threefry(key, (0, i))
    uint32_t kf0, kf1, kp0, kp1;
    threefry2x32(0u, 42u, 0u, 0u, kf0, kf1);   // kflip
    threefry2x32(0u, 42u, 0u, 1u, kp0, kp1);   // kparams

    // flip mask
    float uf = jax_uniform_elem(kf0, kf1, b, 0.0f, 1.0f);
    int flip = (uf > 0.5f) ? 1 : 0;

    // H, W from metadata column (pre-flip x)
    size_t base = (size_t)b * C_DIM * HM * WM_META;
    float Hf = x[base + (WM_META - 1)];
    float Wf = x[base + (size_t)HM * WM_META + (WM_META - 1)];
    float area = Hf * Wf;

    const float log_lo = -0.22314355131420976f;  // float(np.log(0.8))
    const float log_hi =  0.22314355131420976f;  // float(np.log(1.25))

    float fi = -1.0f, fj = -1.0f, fh = -1.0f, fw = -1.0f;
    bool success = false;

    for (int t = 0; t < N_TRIES; ++t) {
        // fold_in(kparams, t) = both words of threefry(kparams, (0, t))
        uint32_t f0, f1;
        threefry2x32(kp0, kp1, 0u, (uint32_t)t, f0, f1);
        // partitionable split(folded, 4): child q = threefry(folded, (0, q))
        uint32_t k10, k11, k20, k21, k30, k31, k40, k41;
        threefry2x32(f0, f1, 0u, 0u, k10, k11);
        threefry2x32(f0, f1, 0u, 1u, k20, k21);
        threefry2x32(f0, f1, 0u, 2u, k30, k31);
        threefry2x32(f0, f1, 0u, 3u, k40, k41);

        float u1 = jax_uniform_elem(k10, k11, b, 0.1f, 1.0f);
        float u2 = jax_uniform_elem(k20, k21, b, log_lo, log_hi);
        float u3 = jax_uniform_elem(k30, k31, b, 0.0f, 1.0f);
        float u4 = jax_uniform_elem(k40, k41, b, 0.0f, 1.0f);

        float ta = area * u1;
        float aspect = expf(u2);
        float cw = rintf(sqrtf(ta * aspect));   // rintf = round-half-even = jnp.round
        float ch = rintf(sqrtf(ta / aspect));

        bool valid = (cw > 0.0f) && (cw <= Wf) && (ch > 0.0f) && (ch <= Hf) && (!success);

        float max_i = fmaxf(Hf - ch + 1.0f, 1.0f);
        float max_j = fmaxf(Wf - cw + 1.0f, 1.0f);
        float ri = floorf(u3 * max_i);
        float rj = floorf(u4 * max_j);

        if (valid) { fh = ch; fw = cw; fi = ri; fj = rj; success = true; }
    }

    if (!success) {
        float in_ratio = Wf / Hf;
        float fbw = (in_ratio > 1.25f) ? rintf(Hf * 1.25f) : Wf;
        float fbh = (in_ratio < 0.8f)  ? rintf(Wf / 0.8f)  : Hf;
        fi = floorf((Hf - fbh) / 2.0f);
        fj = floorf((Wf - fbw) / 2.0f);
        fh = fbh; fw = fbw;
    }

    params[b * 5 + 0] = flip;
    params[b * 5 + 1] = (int)fi;
    params[b * 5 + 2] = (int)fj;
    params[b * 5 + 3] = (int)fh;
    params[b * 5 + 4] = (int)fw;
}

// ---------------- Kernel 2: flip + crop + bilinear resize -----------------
__global__ void __launch_bounds__(256)
resize_kernel(const float* __restrict__ x, const int* __restrict__ params,
              float* __restrict__ out) {
#pragma clang fp contract(off)
    int idx = blockIdx.x * 256 + threadIdx.x;
    const int total = B_DIM * C_DIM * OSIZE * OSIZE;
    if (idx >= total) return;

    int ox = idx % OSIZE;
    int tmp = idx / OSIZE;
    int oy = tmp % OSIZE;
    tmp /= OSIZE;
    int c = tmp % C_DIM;
    int b = tmp / C_DIM;

    int flip = params[b * 5 + 0];
    int pi   = params[b * 5 + 1];
    int pj   = params[b * 5 + 2];
    int ph   = params[b * 5 + 3];
    int pw   = params[b * 5 + 4];

    float hf = (float)ph, wf = (float)pw;

    // ys = clip((oy+0.5)*hf/224 - 0.5, 0, hf-1)
    float ys = ((float)oy + 0.5f) * hf;
    ys = ys / 224.0f;
    ys = ys - 0.5f;
    ys = fminf(fmaxf(ys, 0.0f), hf - 1.0f);
    float y0f = floorf(ys);
    float wy = ys - y0f;
    int y0 = (int)y0f + pi;
    y0 = min(max(y0, 0), HM - 1);
    int yhi = min(max(pi + ph - 1, 0), HM - 1);
    int y1 = min(max(y0 + 1, 0), yhi);

    float xs = ((float)ox + 0.5f) * wf;
    xs = xs / 224.0f;
    xs = xs - 0.5f;
    xs = fminf(fmaxf(xs, 0.0f), wf - 1.0f);
    float x0f = floorf(xs);
    float wx = xs - x0f;
    int x0 = (int)x0f + pj;
    x0 = min(max(x0, 0), WM - 1);
    int xhi = min(max(pj + pw - 1, 0), WM - 1);
    int x1 = min(max(x0 + 1, 0), xhi);

    // flip maps logical col c -> memory col (512 - c) in the 513-wide image
    // (reference flips the full 513-wide image incl. meta column, then slices)
    int mx0 = flip ? (WM - x0) : x0;
    int mx1 = flip ? (WM - x1) : x1;

    const float* img = x + ((size_t)(b * C_DIM + c)) * HM * WM_META;
    const float* row0 = img + (size_t)y0 * WM_META;
    const float* row1 = img + (size_t)y1 * WM_META;
    float g00 = row0[mx0];
    float g01 = row0[mx1];
    float g10 = row1[mx0];
    float g11 = row1[mx1];

    float top = (1.0f - wx) * g00 + wx * g01;
    float bot = (1.0f - wx) * g10 + wx * g11;
    out[idx] = (1.0f - wy) * top + wy * bot;
}

extern "C" void kernel_launch(void* const* d_in, const int* in_sizes, int n_in,
                              void* d_out, int out_size, void* d_ws, size_t ws_size,
                              hipStream_t stream) {
    const float* x = (const float*)d_in[0];
    float* out = (float*)d_out;
    int* params = (int*)d_ws;   // 64*5 ints = 1280 bytes

    params_kernel<<<1, 64, 0, stream>>>(x, params);

    const int total = B_DIM * C_DIM * OSIZE * OSIZE;  // 9,633,792
    const int blocks = (total + 255) / 256;           // 37,632
    resize_kernel<<<blocks, 256, 0, stream>>>(x, params, out);
}

// Round 3
// 276.591 us; speedup vs baseline: 1.0289x; 1.0289x over previous
//
#include <hip/hip_runtime.h>
#include <stdint.h>

#define B_DIM 64
#define C_DIM 3
#define HM 512
#define WM_META 513
#define WM 512
#define OSIZE 224
#define N_TRIES 10

// ---------------- Threefry-2x32 (20 rounds), exactly JAX's ----------------
__device__ __forceinline__ uint32_t rotl32(uint32_t v, int d) {
    return (v << d) | (v >> (32 - d));
}

__device__ __forceinline__ void threefry2x32(uint32_t k0, uint32_t k1,
                                             uint32_t x0, uint32_t x1,
                                             uint32_t& o0, uint32_t& o1) {
    const uint32_t ks0 = k0, ks1 = k1, ks2 = k0 ^ k1 ^ 0x1BD11BDAu;
    x0 += ks0; x1 += ks1;
    // rounds 1-4: rot {13,15,26,6}, inject (ks1, ks2+1)
    x0 += x1; x1 = rotl32(x1, 13); x1 ^= x0;
    x0 += x1; x1 = rotl32(x1, 15); x1 ^= x0;
    x0 += x1; x1 = rotl32(x1, 26); x1 ^= x0;
    x0 += x1; x1 = rotl32(x1,  6); x1 ^= x0;
    x0 += ks1; x1 += ks2 + 1u;
    // rounds 5-8: rot {17,29,16,24}, inject (ks2, ks0+2)
    x0 += x1; x1 = rotl32(x1, 17); x1 ^= x0;
    x0 += x1; x1 = rotl32(x1, 29); x1 ^= x0;
    x0 += x1; x1 = rotl32(x1, 16); x1 ^= x0;
    x0 += x1; x1 = rotl32(x1, 24); x1 ^= x0;
    x0 += ks2; x1 += ks0 + 2u;
    // rounds 9-12
    x0 += x1; x1 = rotl32(x1, 13); x1 ^= x0;
    x0 += x1; x1 = rotl32(x1, 15); x1 ^= x0;
    x0 += x1; x1 = rotl32(x1, 26); x1 ^= x0;
    x0 += x1; x1 = rotl32(x1,  6); x1 ^= x0;
    x0 += ks0; x1 += ks1 + 3u;
    // rounds 13-16
    x0 += x1; x1 = rotl32(x1, 17); x1 ^= x0;
    x0 += x1; x1 = rotl32(x1, 29); x1 ^= x0;
    x0 += x1; x1 = rotl32(x1, 16); x1 ^= x0;
    x0 += x1; x1 = rotl32(x1, 24); x1 ^= x0;
    x0 += ks1; x1 += ks2 + 4u;
    // rounds 17-20
    x0 += x1; x1 = rotl32(x1, 13); x1 ^= x0;
    x0 += x1; x1 = rotl32(x1, 15); x1 ^= x0;
    x0 += x1; x1 = rotl32(x1, 26); x1 ^= x0;
    x0 += x1; x1 = rotl32(x1,  6); x1 ^= x0;
    x0 += ks2; x1 += ks0 + 5u;
    o0 = x0; o1 = x1;
}

// Partitionable-threefry uniform (JAX >= 0.4.30 default):
// element b: counter = 64-bit iota -> (hi=0, lo=b); bits = word0 ^ word1;
// u = bitcast((bits>>9)|0x3f800000)-1; val = u*(hi-lo)+lo (no FMA); max(lo,val).
__device__ __forceinline__ float jax_uniform_elem(uint32_t k0, uint32_t k1, int b,
                                                  float lo, float hi) {
#pragma clang fp contract(off)
    uint32_t w0, w1;
    threefry2x32(k0, k1, 0u, (uint32_t)b, w0, w1);
    uint32_t bits = w0 ^ w1;
    uint32_t fb = (bits >> 9) | 0x3f800000u;
    float u = __uint_as_float(fb) - 1.0f;   // [0,1)
    float d = hi - lo;
    float v = u * d + lo;
    return fmaxf(lo, v);
}

// ---------------- Kernel 1: per-batch params (flip, i, j, h, w) -----------
__global__ void __launch_bounds__(64)
params_kernel(const float* __restrict__ x, int* __restrict__ params) {
#pragma clang fp contract(off)
    int b = threadIdx.x;
    if (b >= B_DIM) return;

    // root key = jax.random.key(42) -> (0, 42)
    // partitionable split: child i = both words of threefry(key, (0, i))
    uint32_t kf0, kf1, kp0, kp1;
    threefry2x32(0u, 42u, 0u, 0u, kf0, kf1);   // kflip
    threefry2x32(0u, 42u, 0u, 1u, kp0, kp1);   // kparams

    // flip mask
    float uf = jax_uniform_elem(kf0, kf1, b, 0.0f, 1.0f);
    int flip = (uf > 0.5f) ? 1 : 0;

    // H, W from metadata column (pre-flip x)
    size_t base = (size_t)b * C_DIM * HM * WM_META;
    float Hf = x[base + (WM_META - 1)];
    float Wf = x[base + (size_t)HM * WM_META + (WM_META - 1)];
    float area = Hf * Wf;

    const float log_lo = -0.22314355131420976f;  // float(np.log(0.8))
    const float log_hi =  0.22314355131420976f;  // float(np.log(1.25))

    float fi = -1.0f, fj = -1.0f, fh = -1.0f, fw = -1.0f;
    bool success = false;

    for (int t = 0; t < N_TRIES; ++t) {
        // fold_in(kparams, t) = both words of threefry(kparams, (0, t))
        uint32_t f0, f1;
        threefry2x32(kp0, kp1, 0u, (uint32_t)t, f0, f1);
        // partitionable split(folded, 4): child q = threefry(folded, (0, q))
        uint32_t k10, k11, k20, k21, k30, k31, k40, k41;
        threefry2x32(f0, f1, 0u, 0u, k10, k11);
        threefry2x32(f0, f1, 0u, 1u, k20, k21);
        threefry2x32(f0, f1, 0u, 2u, k30, k31);
        threefry2x32(f0, f1, 0u, 3u, k40, k41);

        float u1 = jax_uniform_elem(k10, k11, b, 0.1f, 1.0f);
        float u2 = jax_uniform_elem(k20, k21, b, log_lo, log_hi);
        float u3 = jax_uniform_elem(k30, k31, b, 0.0f, 1.0f);
        float u4 = jax_uniform_elem(k40, k41, b, 0.0f, 1.0f);

        float ta = area * u1;
        float aspect = expf(u2);
        float cw = rintf(sqrtf(ta * aspect));   // rintf = round-half-even = jnp.round
        float ch = rintf(sqrtf(ta / aspect));

        bool valid = (cw > 0.0f) && (cw <= Wf) && (ch > 0.0f) && (ch <= Hf) && (!success);

        float max_i = fmaxf(Hf - ch + 1.0f, 1.0f);
        float max_j = fmaxf(Wf - cw + 1.0f, 1.0f);
        float ri = floorf(u3 * max_i);
        float rj = floorf(u4 * max_j);

        if (valid) { fh = ch; fw = cw; fi = ri; fj = rj; success = true; }
    }

    if (!success) {
        float in_ratio = Wf / Hf;
        float fbw = (in_ratio > 1.25f) ? rintf(Hf * 1.25f) : Wf;
        float fbh = (in_ratio < 0.8f)  ? rintf(Wf / 0.8f)  : Hf;
        fi = floorf((Hf - fbh) / 2.0f);
        fj = floorf((Wf - fbw) / 2.0f);
        fh = fbh; fw = fbw;
    }

    params[b * 5 + 0] = flip;
    params[b * 5 + 1] = (int)fi;
    params[b * 5 + 2] = (int)fj;
    params[b * 5 + 3] = (int)fh;
    params[b * 5 + 4] = (int)fw;
}

// ---------------- Kernel 2: flip + crop + bilinear resize (4-wide) --------
// Each thread produces 4 contiguous output pixels (one float4 store).
// Coordinate math is bit-identical to the validated scalar version.
__global__ void __launch_bounds__(256)
resize_kernel(const float* __restrict__ x, const int* __restrict__ params,
              float* __restrict__ out) {
#pragma clang fp contract(off)
    const int OX_UNITS = OSIZE / 4;  // 56
    int idx = blockIdx.x * 256 + threadIdx.x;
    const int total = B_DIM * C_DIM * OSIZE * OX_UNITS;  // 2,408,448
    if (idx >= total) return;

    int oxu = idx % OX_UNITS;
    int tmp = idx / OX_UNITS;
    int oy = tmp % OSIZE;
    tmp /= OSIZE;
    int c = tmp % C_DIM;
    int b = tmp / C_DIM;

    int flip = params[b * 5 + 0];
    int pi   = params[b * 5 + 1];
    int pj   = params[b * 5 + 2];
    int ph   = params[b * 5 + 3];
    int pw   = params[b * 5 + 4];

    float hf = (float)ph, wf = (float)pw;

    // y math (once per 4 pixels): ys = clip((oy+0.5)*hf/224 - 0.5, 0, hf-1)
    float ys = ((float)oy + 0.5f) * hf;
    ys = ys / 224.0f;
    ys = ys - 0.5f;
    ys = fminf(fmaxf(ys, 0.0f), hf - 1.0f);
    float y0f = floorf(ys);
    float wy = ys - y0f;
    int y0 = (int)y0f + pi;
    y0 = min(max(y0, 0), HM - 1);
    int yhi = min(max(pi + ph - 1, 0), HM - 1);
    int y1 = min(max(y0 + 1, 0), yhi);

    int xhi = min(max(pj + pw - 1, 0), WM - 1);

    const float* img  = x + ((size_t)(b * C_DIM + c)) * HM * WM_META;
    const float* row0 = img + (size_t)y0 * WM_META;
    const float* row1 = img + (size_t)y1 * WM_META;

    float res[4];
#pragma unroll
    for (int k = 0; k < 4; ++k) {
        int ox = oxu * 4 + k;
        float xs = ((float)ox + 0.5f) * wf;
        xs = xs / 224.0f;
        xs = xs - 0.5f;
        xs = fminf(fmaxf(xs, 0.0f), wf - 1.0f);
        float x0f = floorf(xs);
        float wx = xs - x0f;
        int x0 = (int)x0f + pj;
        x0 = min(max(x0, 0), WM - 1);
        int x1 = min(max(x0 + 1, 0), xhi);

        // flip maps logical col -> memory col (512 - col) in the 513-wide image
        int mx0 = flip ? (WM - x0) : x0;
        int mx1 = flip ? (WM - x1) : x1;

        float g00 = row0[mx0];
        float g01 = row0[mx1];
        float g10 = row1[mx0];
        float g11 = row1[mx1];

        float top = (1.0f - wx) * g00 + wx * g01;
        float bot = (1.0f - wx) * g10 + wx * g11;
        res[k] = (1.0f - wy) * top + wy * bot;
    }

    float4 v = make_float4(res[0], res[1], res[2], res[3]);
    *reinterpret_cast<float4*>(out + (size_t)idx * 4) = v;
}

extern "C" void kernel_launch(void* const* d_in, const int* in_sizes, int n_in,
                              void* d_out, int out_size, void* d_ws, size_t ws_size,
                              hipStream_t stream) {
    const float* x = (const float*)d_in[0];
    float* out = (float*)d_out;
    int* params = (int*)d_ws;   // 64*5 ints = 1280 bytes

    params_kernel<<<1, 64, 0, stream>>>(x, params);

    const int total = B_DIM * C_DIM * OSIZE * (OSIZE / 4);  // 2,408,448
    const int blocks = (total + 255) / 256;                 // 9408
    resize_kernel<<<blocks, 256, 0, stream>>>(x, params, out);
}

// Round 4
// 275.290 us; speedup vs baseline: 1.0338x; 1.0047x over previous
//
#include <hip/hip_runtime.h>
#include <stdint.h>

#define B_DIM 64
#define C_DIM 3
#define HM 512
#define WM_META 513
#define WM 512
#define OSIZE 224
#define N_TRIES 10
#define OX_UNITS (OSIZE / 4)                      // 56
#define UNITS_PER_B (C_DIM * OSIZE * OX_UNITS)    // 37,632 = 147 * 256
#define BLOCKS_PER_B (UNITS_PER_B / 256)          // 147

// ---------------- Threefry-2x32 (20 rounds), exactly JAX's ----------------
__device__ __forceinline__ uint32_t rotl32(uint32_t v, int d) {
    return (v << d) | (v >> (32 - d));
}

__device__ __forceinline__ void threefry2x32(uint32_t k0, uint32_t k1,
                                             uint32_t x0, uint32_t x1,
                                             uint32_t& o0, uint32_t& o1) {
    const uint32_t ks0 = k0, ks1 = k1, ks2 = k0 ^ k1 ^ 0x1BD11BDAu;
    x0 += ks0; x1 += ks1;
    x0 += x1; x1 = rotl32(x1, 13); x1 ^= x0;
    x0 += x1; x1 = rotl32(x1, 15); x1 ^= x0;
    x0 += x1; x1 = rotl32(x1, 26); x1 ^= x0;
    x0 += x1; x1 = rotl32(x1,  6); x1 ^= x0;
    x0 += ks1; x1 += ks2 + 1u;
    x0 += x1; x1 = rotl32(x1, 17); x1 ^= x0;
    x0 += x1; x1 = rotl32(x1, 29); x1 ^= x0;
    x0 += x1; x1 = rotl32(x1, 16); x1 ^= x0;
    x0 += x1; x1 = rotl32(x1, 24); x1 ^= x0;
    x0 += ks2; x1 += ks0 + 2u;
    x0 += x1; x1 = rotl32(x1, 13); x1 ^= x0;
    x0 += x1; x1 = rotl32(x1, 15); x1 ^= x0;
    x0 += x1; x1 = rotl32(x1, 26); x1 ^= x0;
    x0 += x1; x1 = rotl32(x1,  6); x1 ^= x0;
    x0 += ks0; x1 += ks1 + 3u;
    x0 += x1; x1 = rotl32(x1, 17); x1 ^= x0;
    x0 += x1; x1 = rotl32(x1, 29); x1 ^= x0;
    x0 += x1; x1 = rotl32(x1, 16); x1 ^= x0;
    x0 += x1; x1 = rotl32(x1, 24); x1 ^= x0;
    x0 += ks1; x1 += ks2 + 4u;
    x0 += x1; x1 = rotl32(x1, 13); x1 ^= x0;
    x0 += x1; x1 = rotl32(x1, 15); x1 ^= x0;
    x0 += x1; x1 = rotl32(x1, 26); x1 ^= x0;
    x0 += x1; x1 = rotl32(x1,  6); x1 ^= x0;
    x0 += ks2; x1 += ks0 + 5u;
    o0 = x0; o1 = x1;
}

// Partitionable-threefry raw bits for element b: counter (hi=0, lo=b),
// bits = word0 ^ word1. (JAX >= 0.4.30 default threefry_partitionable.)
__device__ __forceinline__ uint32_t jax_bits_elem(uint32_t k0, uint32_t k1, int b) {
    uint32_t w0, w1;
    threefry2x32(k0, k1, 0u, (uint32_t)b, w0, w1);
    return w0 ^ w1;
}

__device__ __forceinline__ float bits_to_uniform(uint32_t bits, float lo, float hi) {
#pragma clang fp contract(off)
    uint32_t fb = (bits >> 9) | 0x3f800000u;
    float u = __uint_as_float(fb) - 1.0f;   // [0,1)
    float d = hi - lo;
    float v = u * d + lo;
    return fmaxf(lo, v);
}

// ---------------- Fused kernel: params (per-block, parallel) + resize -----
// Grid: 64 * 147 = 9408 blocks of 256. Block handles 256 float4-units of one
// batch image b = blockIdx.x / 147. Lanes 0..39 compute the 40 (try,key)
// uniform chains in parallel, lane 40 the flip chain; selection is then run
// redundantly by all threads from LDS (uniform branches, broadcast reads).
__global__ void __launch_bounds__(256)
fused_kernel(const float* __restrict__ x, float* __restrict__ out) {
#pragma clang fp contract(off)
    __shared__ float u_lds[41];

    const int tid = threadIdx.x;
    const int b = blockIdx.x / BLOCKS_PER_B;

    // ---- parallel RNG phase ----
    if (tid < 41) {
        if (tid < 40) {
            int t = tid >> 2;      // try 0..9
            int q = tid & 3;       // key 0..3
            // kparams = threefry(root=(0,42), (0,1))
            uint32_t kp0, kp1;
            threefry2x32(0u, 42u, 0u, 1u, kp0, kp1);
            // fold_in(kparams, t) = threefry(kparams, (0,t))
            uint32_t f0, f1;
            threefry2x32(kp0, kp1, 0u, (uint32_t)t, f0, f1);
            // split(folded,4) child q = threefry(folded, (0,q))
            uint32_t kq0, kq1;
            threefry2x32(f0, f1, 0u, (uint32_t)q, kq0, kq1);
            uint32_t bits = jax_bits_elem(kq0, kq1, b);
            const float log_lo = -0.22314355131420976f;  // float(np.log(0.8))
            const float log_hi =  0.22314355131420976f;
            float lo = (q == 0) ? 0.1f : (q == 1) ? log_lo : 0.0f;
            float hi = (q == 0) ? 1.0f : (q == 1) ? log_hi : 1.0f;
            u_lds[tid] = bits_to_uniform(bits, lo, hi);
        } else {
            // flip: kflip = threefry(root, (0,0)); u = uniform elem b
            uint32_t kf0, kf1;
            threefry2x32(0u, 42u, 0u, 0u, kf0, kf1);
            uint32_t bits = jax_bits_elem(kf0, kf1, b);
            u_lds[40] = bits_to_uniform(bits, 0.0f, 1.0f);
        }
    }
    __syncthreads();

    // ---- selection (redundant across all threads; uniform per block) ----
    size_t base = (size_t)b * C_DIM * HM * WM_META;
    float Hf = x[base + (WM_META - 1)];
    float Wf = x[base + (size_t)HM * WM_META + (WM_META - 1)];
    float area = Hf * Wf;

    int flip = (u_lds[40] > 0.5f) ? 1 : 0;

    float fi = -1.0f, fj = -1.0f, fh = -1.0f, fw = -1.0f;
    bool success = false;
    for (int t = 0; t < N_TRIES; ++t) {
        float u1 = u_lds[t * 4 + 0];
        float u2 = u_lds[t * 4 + 1];
        float u3 = u_lds[t * 4 + 2];
        float u4 = u_lds[t * 4 + 3];

        float ta = area * u1;
        float aspect = expf(u2);
        float cw = rintf(sqrtf(ta * aspect));   // rintf = round-half-even = jnp.round
        float ch = rintf(sqrtf(ta / aspect));

        bool valid = (cw > 0.0f) && (cw <= Wf) && (ch > 0.0f) && (ch <= Hf) && (!success);

        float max_i = fmaxf(Hf - ch + 1.0f, 1.0f);
        float max_j = fmaxf(Wf - cw + 1.0f, 1.0f);
        float ri = floorf(u3 * max_i);
        float rj = floorf(u4 * max_j);

        if (valid) { fh = ch; fw = cw; fi = ri; fj = rj; success = true; }
    }
    if (!success) {
        float in_ratio = Wf / Hf;
        float fbw = (in_ratio > 1.25f) ? rintf(Hf * 1.25f) : Wf;
        float fbh = (in_ratio < 0.8f)  ? rintf(Wf / 0.8f)  : Hf;
        fi = floorf((Hf - fbh) / 2.0f);
        fj = floorf((Wf - fbw) / 2.0f);
        fh = fbh; fw = fbw;
    }

    int pi = (int)fi, pj = (int)fj, ph = (int)fh, pw = (int)fw;

    // ---- resize phase (bit-identical math to validated round-3 kernel) ----
    int idx = blockIdx.x * 256 + tid;
    int oxu = idx % OX_UNITS;
    int tmp = idx / OX_UNITS;
    int oy = tmp % OSIZE;
    tmp /= OSIZE;
    int c = tmp % C_DIM;
    // note: tmp / C_DIM == b by construction (147*256 units per b)

    float hf = (float)ph, wf = (float)pw;

    float ys = ((float)oy + 0.5f) * hf;
    ys = ys / 224.0f;
    ys = ys - 0.5f;
    ys = fminf(fmaxf(ys, 0.0f), hf - 1.0f);
    float y0f = floorf(ys);
    float wy = ys - y0f;
    int y0 = (int)y0f + pi;
    y0 = min(max(y0, 0), HM - 1);
    int yhi = min(max(pi + ph - 1, 0), HM - 1);
    int y1 = min(max(y0 + 1, 0), yhi);

    int xhi = min(max(pj + pw - 1, 0), WM - 1);

    const float* img  = x + ((size_t)(b * C_DIM + c)) * HM * WM_META;
    const float* row0 = img + (size_t)y0 * WM_META;
    const float* row1 = img + (size_t)y1 * WM_META;

    float res[4];
#pragma unroll
    for (int k = 0; k < 4; ++k) {
        int ox = oxu * 4 + k;
        float xs = ((float)ox + 0.5f) * wf;
        xs = xs / 224.0f;
        xs = xs - 0.5f;
        xs = fminf(fmaxf(xs, 0.0f), wf - 1.0f);
        float x0f = floorf(xs);
        float wx = xs - x0f;
        int x0 = (int)x0f + pj;
        x0 = min(max(x0, 0), WM - 1);
        int x1 = min(max(x0 + 1, 0), xhi);

        // flip maps logical col -> memory col (512 - col) in the 513-wide image
        int mx0 = flip ? (WM - x0) : x0;
        int mx1 = flip ? (WM - x1) : x1;

        float g00 = row0[mx0];
        float g01 = row0[mx1];
        float g10 = row1[mx0];
        float g11 = row1[mx1];

        float top = (1.0f - wx) * g00 + wx * g01;
        float bot = (1.0f - wx) * g10 + wx * g11;
        res[k] = (1.0f - wy) * top + wy * bot;
    }

    float4 v = make_float4(res[0], res[1], res[2], res[3]);
    *reinterpret_cast<float4*>(out + (size_t)idx * 4) = v;
}

extern "C" void kernel_launch(void* const* d_in, const int* in_sizes, int n_in,
                              void* d_out, int out_size, void* d_ws, size_t ws_size,
                              hipStream_t stream) {
    const float* x = (const float*)d_in[0];
    float* out = (float*)d_out;

    const int blocks = B_DIM * BLOCKS_PER_B;  // 9408
    fused_kernel<<<blocks, 256, 0, stream>>>(x, out);
}